// Round 1
// baseline (241.538 us; speedup 1.0000x reference)
//
#include <hip/hip_runtime.h>
#include <hip/hip_bf16.h>

#define NE 1600000
#define NN 100000

typedef __attribute__((ext_vector_type(8))) short s16x8;
typedef __attribute__((ext_vector_type(4))) float f32x4;
typedef __attribute__((ext_vector_type(4))) int i32x4;

__device__ __forceinline__ ushort f2b(float v) {
  union { __hip_bfloat16 h; ushort u; } c; c.h = __float2bfloat16(v); return c.u;
}

// Store bf16 into swizzled per-wave h-tile: 32 rows x 128 cols, row stride 256B,
// 16B slot index XORed with (row&7) to kill the D=128 bank conflict.
__device__ __forceinline__ void st_h(char* hbuf, int row, int col, ushort v) {
  *(ushort*)(hbuf + (row << 8) + (((col >> 3) ^ (row & 7)) << 4) + ((col & 7) << 1)) = v;
}

// ---- prep: rearrange weights into MFMA B-fragment order (bf16) ----
// B-frag for chunk (kb,nb): lane l holds B[kb*32 + (l>>4)*8 + j][nb*16 + (l&15)], j=0..7.
// Stored frag-major: elem index = ((kb*NF+nb)*64 + lane)*8 + j.
__global__ void prep_weights(const float* s0, const float* s1, const float* s2, const float* s3,
                             const float* s4, const float* s5, const float* s6, const float* s7,
                             ushort* dst) {
  const int Ks[8]   = {10, 128, 128, 128, 7, 128, 128, 128};
  const int Ns[8]   = {128, 128, 128, 2, 128, 128, 128, 2};
  const int NFs[8]  = {8, 8, 8, 1, 8, 8, 8, 1};
  const int KCs[8]  = {1, 4, 4, 4, 1, 4, 4, 4};
  const int offs[8] = {0, 4096, 20480, 36864, 38912, 43008, 59392, 75776};
  const float* srcs[8] = {s0, s1, s2, s3, s4, s5, s6, s7};
  int b = blockIdx.x;
  int K = Ks[b], N = Ns[b], NF = NFs[b];
  int cnt = KCs[b] * NF * 512;
  const float* src = srcs[b];
  ushort* d = dst + offs[b];
  for (int idx = threadIdx.x; idx < cnt; idx += blockDim.x) {
    int f = idx >> 9, r = idx & 511, lane = r >> 3, j = r & 7;
    int kb = f / NF, nb = f - kb * NF;
    int k = kb * 32 + ((lane >> 4) << 3) + j;
    int n = (nb << 4) + (lane & 15);
    float v = (k < K && n < N) ? src[k * N + n] : 0.f;
    d[idx] = f2b(v);
  }
}

// ---- main: MODE 0 = edge MLP + atomic scatter, MODE 1 = node-update MLP + output ----
template <int MODE>
__global__ __launch_bounds__(512)
void gnn_kernel(const float* __restrict__ nodes,
                const int* __restrict__ eidx,
                float* __restrict__ pooled,
                const ushort* __restrict__ wsrc,
                const float* __restrict__ b0g, const float* __restrict__ b1g,
                const float* __restrict__ b2g, const float* __restrict__ b3g,
                float* __restrict__ out) {
  extern __shared__ char smem[];
  ushort* wlds = (ushort*)smem;                 // 38912 ushort = 77824 B
  float* bias0 = (float*)(smem + 77824);        // 128
  float* bias1 = bias0 + 128;
  float* bias2 = bias1 + 128;
  float* bias3 = bias2 + 128;                   // 16
  char* stage = smem + 79424;                   // 8 waves * (2048 xbuf + 8192 hbuf)

  {
    i32x4* dw = (i32x4*)wlds;
    const i32x4* sw = (const i32x4*)wsrc;
    for (int i = threadIdx.x; i < 4864; i += 512) dw[i] = sw[i];
    for (int i = threadIdx.x; i < 128; i += 512) {
      bias0[i] = b0g[i]; bias1[i] = b1g[i]; bias2[i] = b2g[i];
    }
    if (threadIdx.x < 16) bias3[threadIdx.x] = (threadIdx.x < 2) ? b3g[threadIdx.x] : 0.f;
    i32x4 z = {0, 0, 0, 0};
    i32x4* sz = (i32x4*)stage;
    for (int i = threadIdx.x; i < 5120; i += 512) sz[i] = z;  // zero staging (K-padding)
  }
  __syncthreads();

  const int wv = threadIdx.x >> 6;
  const int l = threadIdx.x & 63;
  char* xbuf = stage + wv * 10240;   // 32 rows x 32 cols bf16, row stride 64B, swizzle (row&3)
  char* hbuf = xbuf + 2048;          // 32 rows x 128 cols bf16, row stride 256B, swizzle (row&7)
  const int q = l >> 4;
  const int m16 = l & 15;

  const ushort* W0 = wlds;
  const ushort* W1 = wlds + 4096;
  const ushort* W2 = wlds + 20480;
  const ushort* W3 = wlds + 36864;

  int wid = blockIdx.x * 8 + wv;
  int nwv = gridDim.x * 8;
  int NB = (MODE == 0) ? (NE / 32) : (NN / 32);

#pragma unroll 1
  for (int b = wid; b < NB; b += nwv) {
    int rbase = b << 5;
    // ---- gather 32 rows into xbuf ----
    {
      int i = l & 31, p = l >> 5;
      if (MODE == 0) {
        int idx = eidx[p * NE + rbase + i];
        const float* np_ = nodes + idx * 5;
#pragma unroll
        for (int d0 = 0; d0 < 5; d0++) {
          int col = p * 5 + d0;
          *(ushort*)(xbuf + (i << 6) + (((col >> 3) ^ (i & 3)) << 4) + ((col & 7) << 1)) =
              f2b(np_[d0]);
        }
      } else {
        int n = rbase + i;
        if (p == 0) {
#pragma unroll
          for (int d0 = 0; d0 < 5; d0++) {
            int col = d0;
            *(ushort*)(xbuf + (i << 6) + (((col >> 3) ^ (i & 3)) << 4) + ((col & 7) << 1)) =
                f2b(nodes[n * 5 + d0]);
          }
        } else {
#pragma unroll
          for (int d0 = 0; d0 < 2; d0++) {
            int col = 5 + d0;
            *(ushort*)(xbuf + (i << 6) + (((col >> 3) ^ (i & 3)) << 4) + ((col & 7) << 1)) =
                f2b(pooled[n * 2 + d0]);
          }
        }
      }
    }
    // ---- layer 0: K=32 (padded), N=128 ----
    s16x8 a0[2];
#pragma unroll
    for (int mt = 0; mt < 2; mt++) {
      int row = (mt << 4) + m16;
      a0[mt] = *(const s16x8*)(xbuf + (row << 6) + ((q ^ (row & 3)) << 4));
    }
#pragma unroll
    for (int nb = 0; nb < 8; nb++) {
      f32x4 acc0 = {0, 0, 0, 0}, acc1 = {0, 0, 0, 0};
      s16x8 bf = *(const s16x8*)(W0 + (((nb << 6) + l) << 3));
      acc0 = __builtin_amdgcn_mfma_f32_16x16x32_bf16(a0[0], bf, acc0, 0, 0, 0);
      acc1 = __builtin_amdgcn_mfma_f32_16x16x32_bf16(a0[1], bf, acc1, 0, 0, 0);
      int col = (nb << 4) + m16;
      float bs = bias0[col];
#pragma unroll
      for (int j = 0; j < 4; j++) {
        int r0 = (q << 2) + j;
        float v0 = acc0[j] + bs; v0 = v0 > 0.f ? v0 : 0.f;
        st_h(hbuf, r0, col, f2b(v0));
        float v1 = acc1[j] + bs; v1 = v1 > 0.f ? v1 : 0.f;
        st_h(hbuf, 16 + r0, col, f2b(v1));
      }
    }
    // ---- layers 1 & 2: K=128, N=128, in-place through hbuf ----
#pragma unroll
    for (int L = 0; L < 2; L++) {
      const ushort* W = L ? W2 : W1;
      const float* bias = L ? bias2 : bias1;
      s16x8 a[2][4];
#pragma unroll
      for (int mt = 0; mt < 2; mt++) {
        int row = (mt << 4) + m16;
#pragma unroll
        for (int kb = 0; kb < 4; kb++)
          a[mt][kb] = *(const s16x8*)(hbuf + (row << 8) + ((((kb << 2) + q) ^ (row & 7)) << 4));
      }
#pragma unroll
      for (int nb = 0; nb < 8; nb++) {
        f32x4 acc0 = {0, 0, 0, 0}, acc1 = {0, 0, 0, 0};
#pragma unroll
        for (int kb = 0; kb < 4; kb++) {
          s16x8 bf = *(const s16x8*)(W + ((((kb << 3) + nb) << 6) + l) * 8);
          acc0 = __builtin_amdgcn_mfma_f32_16x16x32_bf16(a[0][kb], bf, acc0, 0, 0, 0);
          acc1 = __builtin_amdgcn_mfma_f32_16x16x32_bf16(a[1][kb], bf, acc1, 0, 0, 0);
        }
        int col = (nb << 4) + m16;
        float bs = bias[col];
#pragma unroll
        for (int j = 0; j < 4; j++) {
          int r0 = (q << 2) + j;
          float v0 = acc0[j] + bs; v0 = v0 > 0.f ? v0 : 0.f;
          st_h(hbuf, r0, col, f2b(v0));
          float v1 = acc1[j] + bs; v1 = v1 > 0.f ? v1 : 0.f;
          st_h(hbuf, 16 + r0, col, f2b(v1));
        }
      }
    }
    // ---- head: K=128, N=16 (2 valid) ----
    {
      s16x8 a[2][4];
#pragma unroll
      for (int mt = 0; mt < 2; mt++) {
        int row = (mt << 4) + m16;
#pragma unroll
        for (int kb = 0; kb < 4; kb++)
          a[mt][kb] = *(const s16x8*)(hbuf + (row << 8) + ((((kb << 2) + q) ^ (row & 7)) << 4));
      }
      f32x4 acc0 = {0, 0, 0, 0}, acc1 = {0, 0, 0, 0};
#pragma unroll
      for (int kb = 0; kb < 4; kb++) {
        s16x8 bf = *(const s16x8*)(W3 + (((kb << 6) + l) << 3));
        acc0 = __builtin_amdgcn_mfma_f32_16x16x32_bf16(a[0][kb], bf, acc0, 0, 0, 0);
        acc1 = __builtin_amdgcn_mfma_f32_16x16x32_bf16(a[1][kb], bf, acc1, 0, 0, 0);
      }
      if (m16 < 2) {
        float bs = bias3[m16];
#pragma unroll
        for (int j = 0; j < 4; j++) {
          int r0 = (q << 2) + j, r1 = 16 + (q << 2) + j;
          float v0 = acc0[j] + bs, v1 = acc1[j] + bs;
          int g0 = rbase + r0, g1 = rbase + r1;
          if (MODE == 0) {
            int rc0 = eidx[NE + g0], rc1 = eidx[NE + g1];
            unsafeAtomicAdd(&pooled[rc0 * 2 + m16], v0);
            unsafeAtomicAdd(&pooled[rc1 * 2 + m16], v1);
          } else {
            out[g0 * 5 + 2 + m16] = nodes[g0 * 5 + 2 + m16] + v0;
            out[g1 * 5 + 2 + m16] = nodes[g1 * 5 + 2 + m16] + v1;
            if (m16 == 0) {
              out[g0 * 5] = nodes[g0 * 5]; out[g0 * 5 + 4] = nodes[g0 * 5 + 4];
              out[g1 * 5] = nodes[g1 * 5]; out[g1 * 5 + 4] = nodes[g1 * 5 + 4];
            } else {
              out[g0 * 5 + 1] = nodes[g0 * 5 + 1];
              out[g1 * 5 + 1] = nodes[g1 * 5 + 1];
            }
          }
        }
      }
    }
  }
}

extern "C" void kernel_launch(void* const* d_in, const int* in_sizes, int n_in,
                              void* d_out, int out_size, void* d_ws, size_t ws_size,
                              hipStream_t stream) {
  const float* nodes = (const float*)d_in[0];
  const int* eidx = (const int*)d_in[1];
  const float* Wm0 = (const float*)d_in[2];  const float* bm0 = (const float*)d_in[3];
  const float* Wm1 = (const float*)d_in[4];  const float* bm1 = (const float*)d_in[5];
  const float* Wm2 = (const float*)d_in[6];  const float* bm2 = (const float*)d_in[7];
  const float* Wm3 = (const float*)d_in[8];  const float* bm3 = (const float*)d_in[9];
  const float* Wu0 = (const float*)d_in[10]; const float* bu0 = (const float*)d_in[11];
  const float* Wu1 = (const float*)d_in[12]; const float* bu1 = (const float*)d_in[13];
  const float* Wu2 = (const float*)d_in[14]; const float* bu2 = (const float*)d_in[15];
  const float* Wu3 = (const float*)d_in[16]; const float* bu3 = (const float*)d_in[17];

  float* pooled = (float*)d_ws;                       // NN*2 f32 = 800000 B
  ushort* wbuf = (ushort*)((char*)d_ws + 800000);     // 2*38912 ushort prearranged bf16

  hipMemsetAsync(pooled, 0, NN * 2 * sizeof(float), stream);
  prep_weights<<<8, 256, 0, stream>>>(Wm0, Wm1, Wm2, Wm3, Wu0, Wu1, Wu2, Wu3, wbuf);

  size_t lds = 161344;  // 77824 wts + 1600 bias + 8*10240 staging
  gnn_kernel<0><<<256, 512, lds, stream>>>(nodes, eidx, pooled, wbuf,
                                           bm0, bm1, bm2, bm3, nullptr);
  gnn_kernel<1><<<256, 512, lds, stream>>>(nodes, nullptr, pooled, wbuf + 38912,
                                           bu0, bu1, bu2, bu3, (float*)d_out);
}